// Round 1
// baseline (372.184 us; speedup 1.0000x reference)
//
#include <hip/hip_runtime.h>

// RandomEqualize: PIL-style histogram equalization per (batch, channel).
// Input: float32 (64,3,512,512) with exact integer values in [0,255].
// N = 192 channels, P = 262144 pixels/channel.

#define NBINS 256
#define BPC 32  // blocks per channel for hist/apply

// ---------------- Kernel 1: per-channel histogram ----------------
__global__ __launch_bounds__(256) void eq_hist_kernel(
    const float* __restrict__ in, unsigned int* __restrict__ ghist,
    int P, int bpc) {
    // 4 per-wave sub-histograms to reduce LDS atomic contention
    __shared__ unsigned int lh[4][NBINS];
    const int t = threadIdx.x;
    const int wave = t >> 6;

    for (int i = t; i < 4 * NBINS; i += 256)
        ((unsigned int*)lh)[i] = 0u;
    __syncthreads();

    const int chan = blockIdx.x / bpc;
    const int blk  = blockIdx.x % bpc;
    const int chunk = P / bpc;                 // 8192 pixels
    const float4* base =
        (const float4*)(in + (size_t)chan * P + (size_t)blk * chunk);
    const int nvec = chunk / 4;                // 2048 float4

    for (int i = t; i < nvec; i += 256) {
        float4 v = base[i];
        int ix = min(max((int)v.x, 0), 255);
        int iy = min(max((int)v.y, 0), 255);
        int iz = min(max((int)v.z, 0), 255);
        int iw = min(max((int)v.w, 0), 255);
        atomicAdd(&lh[wave][ix], 1u);
        atomicAdd(&lh[wave][iy], 1u);
        atomicAdd(&lh[wave][iz], 1u);
        atomicAdd(&lh[wave][iw], 1u);
    }
    __syncthreads();

    unsigned int s = lh[0][t] + lh[1][t] + lh[2][t] + lh[3][t];
    if (s) atomicAdd(&ghist[chan * NBINS + t], s);
}

// ---------------- Kernel 2: per-channel LUT ----------------
__global__ __launch_bounds__(256) void eq_lut_kernel(
    const unsigned int* __restrict__ ghist, float* __restrict__ glut, int P) {
    __shared__ unsigned int s[NBINS];
    __shared__ int sidx[NBINS];
    const int t = threadIdx.x;
    const int chan = blockIdx.x;

    unsigned int h = ghist[chan * NBINS + t];
    s[t] = h;
    sidx[t] = (h != 0u) ? t : -1;
    __syncthreads();

    // max-reduce to find last nonzero bin index
    for (int off = 128; off > 0; off >>= 1) {
        if (t < off) sidx[t] = max(sidx[t], sidx[t + off]);
        __syncthreads();
    }
    const int last_idx = sidx[0];
    const unsigned int last_val = s[last_idx];  // broadcast
    const int step = (P - (int)last_val) / 255; // >= 0

    // Hillis-Steele inclusive scan over 256 bins
    for (int off = 1; off < NBINS; off <<= 1) {
        unsigned int val = (t >= off) ? s[t - off] : 0u;
        __syncthreads();
        s[t] += val;
        __syncthreads();
    }

    float lv;
    if (step == 0) {
        lv = (float)t;  // pass-through channel: identity LUT
    } else {
        int cs_prev = (t == 0) ? 0 : (int)s[t - 1];
        int l = (cs_prev + (step >> 1)) / step;
        l = min(max(l, 0), 255);
        lv = (float)l;
    }
    glut[chan * NBINS + t] = lv;
}

// ---------------- Kernel 3: apply LUT ----------------
__global__ __launch_bounds__(256) void eq_apply_kernel(
    const float* __restrict__ in, const float* __restrict__ glut,
    float* __restrict__ out, int P, int bpc) {
    __shared__ float slut[NBINS];
    const int t = threadIdx.x;
    const int chan = blockIdx.x / bpc;
    const int blk  = blockIdx.x % bpc;

    slut[t] = glut[chan * NBINS + t];
    __syncthreads();

    const int chunk = P / bpc;
    const size_t base = (size_t)chan * P + (size_t)blk * chunk;
    const float4* vin = (const float4*)(in + base);
    float4* vout = (float4*)(out + base);
    const int nvec = chunk / 4;

    for (int i = t; i < nvec; i += 256) {
        float4 v = vin[i];
        float4 r;
        r.x = slut[min(max((int)v.x, 0), 255)];
        r.y = slut[min(max((int)v.y, 0), 255)];
        r.z = slut[min(max((int)v.z, 0), 255)];
        r.w = slut[min(max((int)v.w, 0), 255)];
        vout[i] = r;
    }
}

extern "C" void kernel_launch(void* const* d_in, const int* in_sizes, int n_in,
                              void* d_out, int out_size, void* d_ws, size_t ws_size,
                              hipStream_t stream) {
    const float* img = (const float*)d_in[0];
    float* out = (float*)d_out;

    const int P = 512 * 512;                 // pixels per channel
    const int total = in_sizes[0];           // 64*3*512*512
    const int N = total / P;                 // 192 channels

    unsigned int* ghist = (unsigned int*)d_ws;
    float* glut = (float*)((char*)d_ws + (size_t)N * NBINS * sizeof(unsigned int));

    // zero the histograms (ws is poisoned with 0xAA before every launch)
    hipMemsetAsync(d_ws, 0, (size_t)N * NBINS * sizeof(unsigned int), stream);

    eq_hist_kernel<<<N * BPC, 256, 0, stream>>>(img, ghist, P, BPC);
    eq_lut_kernel<<<N, 256, 0, stream>>>(ghist, glut, P);
    eq_apply_kernel<<<N * BPC, 256, 0, stream>>>(img, glut, out, P, BPC);
}

// Round 2
// 371.616 us; speedup vs baseline: 1.0015x; 1.0015x over previous
//
#include <hip/hip_runtime.h>

// RandomEqualize: PIL-style histogram equalization per (batch, channel).
// Input: float32 (64,3,512,512) with exact integer values in [0,255].
// N = 192 channels, P = 262144 pixels/channel.

#define NBINS 256
#define BPC 32  // blocks per channel for hist/apply

// ---------------- Kernel 1: per-channel histogram ----------------
// 32 sub-histogram copies, bank-strided: element (bin, copy) lives at
// word bin*32 + copy  ->  LDS bank = copy. Each lane uses copy = lane&31,
// so every ds_add hits its own bank (2 lanes/bank = free), and
// same-address serialization is at most 2-way (lane i vs i+32, same bin).
__global__ __launch_bounds__(256) void eq_hist_kernel(
    const float* __restrict__ in, unsigned int* __restrict__ ghist,
    int P, int bpc) {
    __shared__ unsigned int lh[NBINS * 32];  // 32 KB
    const int t = threadIdx.x;
    const int copy = t & 31;

    for (int i = t; i < NBINS * 32; i += 256) lh[i] = 0u;
    __syncthreads();

    const int chan = blockIdx.x / bpc;
    const int blk  = blockIdx.x % bpc;
    const int chunk = P / bpc;                 // 8192 pixels
    const float4* base =
        (const float4*)(in + (size_t)chan * P + (size_t)blk * chunk);
    const int nvec = chunk / 4;                // 2048 float4

    for (int i = t; i < nvec; i += 256) {
        float4 v = base[i];
        int ix = min(max((int)v.x, 0), 255);
        int iy = min(max((int)v.y, 0), 255);
        int iz = min(max((int)v.z, 0), 255);
        int iw = min(max((int)v.w, 0), 255);
        atomicAdd(&lh[ix * 32 + copy], 1u);
        atomicAdd(&lh[iy * 32 + copy], 1u);
        atomicAdd(&lh[iz * 32 + copy], 1u);
        atomicAdd(&lh[iw * 32 + copy], 1u);
    }
    __syncthreads();

    // Thread t owns bin t. Staggered copy index keeps lanes on distinct banks.
    unsigned int s = 0;
    #pragma unroll
    for (int c = 0; c < 32; ++c)
        s += lh[t * 32 + ((t + c) & 31)];
    atomicAdd(&ghist[chan * NBINS + t], s);
}

// ---------------- Kernel 2: per-channel LUT ----------------
__global__ __launch_bounds__(256) void eq_lut_kernel(
    const unsigned int* __restrict__ ghist, float* __restrict__ glut, int P) {
    __shared__ unsigned int s[NBINS];
    __shared__ int sidx[NBINS];
    const int t = threadIdx.x;
    const int chan = blockIdx.x;

    unsigned int h = ghist[chan * NBINS + t];
    s[t] = h;
    sidx[t] = (h != 0u) ? t : -1;
    __syncthreads();

    // max-reduce to find last nonzero bin index
    for (int off = 128; off > 0; off >>= 1) {
        if (t < off) sidx[t] = max(sidx[t], sidx[t + off]);
        __syncthreads();
    }
    const int last_idx = sidx[0];
    const unsigned int last_val = s[last_idx];  // broadcast
    const int step = (P - (int)last_val) / 255; // >= 0

    // Hillis-Steele inclusive scan over 256 bins
    for (int off = 1; off < NBINS; off <<= 1) {
        unsigned int val = (t >= off) ? s[t - off] : 0u;
        __syncthreads();
        s[t] += val;
        __syncthreads();
    }

    float lv;
    if (step == 0) {
        lv = (float)t;  // pass-through channel: identity LUT
    } else {
        int cs_prev = (t == 0) ? 0 : (int)s[t - 1];
        int l = (cs_prev + (step >> 1)) / step;
        l = min(max(l, 0), 255);
        lv = (float)l;
    }
    glut[chan * NBINS + t] = lv;
}

// ---------------- Kernel 3: apply LUT ----------------
__global__ __launch_bounds__(256) void eq_apply_kernel(
    const float* __restrict__ in, const float* __restrict__ glut,
    float* __restrict__ out, int P, int bpc) {
    __shared__ float slut[NBINS];
    const int t = threadIdx.x;
    const int chan = blockIdx.x / bpc;
    const int blk  = blockIdx.x % bpc;

    slut[t] = glut[chan * NBINS + t];
    __syncthreads();

    const int chunk = P / bpc;
    const size_t base = (size_t)chan * P + (size_t)blk * chunk;
    const float4* vin = (const float4*)(in + base);
    float4* vout = (float4*)(out + base);
    const int nvec = chunk / 4;

    for (int i = t; i < nvec; i += 256) {
        float4 v = vin[i];
        float4 r;
        r.x = slut[min(max((int)v.x, 0), 255)];
        r.y = slut[min(max((int)v.y, 0), 255)];
        r.z = slut[min(max((int)v.z, 0), 255)];
        r.w = slut[min(max((int)v.w, 0), 255)];
        vout[i] = r;
    }
}

extern "C" void kernel_launch(void* const* d_in, const int* in_sizes, int n_in,
                              void* d_out, int out_size, void* d_ws, size_t ws_size,
                              hipStream_t stream) {
    const float* img = (const float*)d_in[0];
    float* out = (float*)d_out;

    const int P = 512 * 512;                 // pixels per channel
    const int total = in_sizes[0];           // 64*3*512*512
    const int N = total / P;                 // 192 channels

    unsigned int* ghist = (unsigned int*)d_ws;
    float* glut = (float*)((char*)d_ws + (size_t)N * NBINS * sizeof(unsigned int));

    // zero the histograms (ws is poisoned with 0xAA before every launch)
    hipMemsetAsync(d_ws, 0, (size_t)N * NBINS * sizeof(unsigned int), stream);

    eq_hist_kernel<<<N * BPC, 256, 0, stream>>>(img, ghist, P, BPC);
    eq_lut_kernel<<<N, 256, 0, stream>>>(ghist, glut, P);
    eq_apply_kernel<<<N * BPC, 256, 0, stream>>>(img, glut, out, P, BPC);
}